// Round 3
// baseline (343.750 us; speedup 1.0000x reference)
//
#include <hip/hip_runtime.h>

#define DIM 512
#define BATCH 65536
#define BM 32
#define THREADS 512
#define TILES 4
#define NBLK (BATCH / (BM * TILES))   // 512 blocks

typedef float f32x4 __attribute__((ext_vector_type(4)));
typedef float f32x16 __attribute__((ext_vector_type(16)));
typedef __bf16 bf16x8 __attribute__((ext_vector_type(8)));

__device__ __forceinline__ unsigned f2bf(float f) {
    unsigned u = __float_as_uint(f);
    return (u + 0x7FFFu + ((u >> 16) & 1u)) >> 16;
}

// Sf in MFMA-B-fragment order: Sf[((k0*16 + np)*64 + lane)*8 + j]
//   = bf16( A[n][k] + A[k][n] ),  n = np*32 + (lane&31),  k = k0*16 + (lane>>5)*8 + j
__global__ void prep_Sfrag(const float* __restrict__ A, unsigned short* __restrict__ Sf) {
    int idx = blockIdx.x * 256 + threadIdx.x;    // 0..32767 : (k0, np, lane)
    int lane = idx & 63;
    int np   = (idx >> 6) & 15;
    int k0   = idx >> 10;
    int n     = np * 32 + (lane & 31);
    int kbase = k0 * 16 + (lane >> 5) * 8;
    unsigned short tmp[8];
    #pragma unroll
    for (int j = 0; j < 8; ++j) {
        int k = kbase + j;
        tmp[j] = (unsigned short)f2bf(A[n * DIM + k] + A[k * DIM + n]);
    }
    *(uint4*)(Sf + (size_t)idx * 8) = *(const uint4*)tmp;
}

// out[b][0:512] = p[b] + q[b].S ; out[b][512:1024] = q[b]
__global__ __launch_bounds__(THREADS, 2)   // VGPR cap 256: room for the reg pipeline
void gemm_kernel(const float* __restrict__ pq,
                 const unsigned short* __restrict__ Sf,
                 float* __restrict__ out) {
    __shared__ unsigned short qs[2][BM * DIM];   // 2 x 32 KB, XOR-swizzled bf16 q
    const int tid  = threadIdx.x;
    const int wid  = tid >> 6;
    const int lane = tid & 63;
    const int row  = lane & 31;
    const int khalf = lane >> 5;
    const size_t brow0 = (size_t)blockIdx.x * (BM * TILES);

    // ---- prologue: stage tile 0 (load q, passthrough to out, bf16+swizzle to LDS)
    #pragma unroll
    for (int j = 0; j < 8; ++j) {
        int flat = (tid + j * THREADS) * 4;
        int r = flat >> 9, c = flat & 511;
        size_t g = (brow0 + r) * 1024 + 512 + c;
        f32x4 v = *(const f32x4*)(pq + g);
        *(f32x4*)(out + g) = v;
        unsigned lo = f2bf(v.x) | (f2bf(v.y) << 16);
        unsigned hi = f2bf(v.z) | (f2bf(v.w) << 16);
        int bo = (c * 2) ^ ((r & 15) << 4);
        *(uint2*)((char*)qs[0] + r * 1024 + bo) = make_uint2(lo, hi);
    }
    __syncthreads();

    const unsigned short* Sfp = Sf + ((size_t)(wid * 2) * 64 + lane) * 8;
    const int col0 = wid * 64 + row;
    const int rsub = 4 * khalf;

    for (int t = 0; t < TILES; ++t) {
        const size_t trow0 = brow0 + (size_t)t * BM;
        const unsigned short* qb = qs[t & 1];

        // ---- issue next-tile q loads (in flight across the whole k-loop)
        f32x4 nv[8];
        if (t + 1 < TILES) {
            #pragma unroll
            for (int j = 0; j < 8; ++j) {
                int flat = (tid + j * THREADS) * 4;
                int r = flat >> 9, c = flat & 511;
                size_t g = (trow0 + BM + r) * 1024 + 512 + c;
                nv[j] = *(const f32x4*)(pq + g);
            }
        }
        // ---- issue this tile's p loads (epilogue operands, hidden under k-loop)
        float pv0[16], pv1[16];
        #pragma unroll
        for (int reg = 0; reg < 16; ++reg) {
            int r = (reg & 3) + 8 * (reg >> 2) + rsub;
            size_t g = (trow0 + r) * 1024;
            pv0[reg] = pq[g + col0];
            pv1[reg] = pq[g + col0 + 32];
        }

        // ---- k-loop, manual depth-2 register pipeline
        f32x16 acc0 = {}, acc1 = {};
        bf16x8 a_c  = *(const bf16x8*)((const char*)qb + row * 1024 +
                                       ((khalf * 16) ^ ((row & 15) << 4)));
        bf16x8 b0_c = *(const bf16x8*)(Sfp);
        bf16x8 b1_c = *(const bf16x8*)(Sfp + 512);
        #pragma unroll
        for (int k0 = 0; k0 < 32; ++k0) {
            bf16x8 a_n, b0_n, b1_n;
            if (k0 < 31) {
                int bo = ((k0 + 1) * 32 + khalf * 16) ^ ((row & 15) << 4);
                a_n  = *(const bf16x8*)((const char*)qb + row * 1024 + bo);
                b0_n = *(const bf16x8*)(Sfp + (size_t)(k0 + 1) * 8192);
                b1_n = *(const bf16x8*)(Sfp + (size_t)(k0 + 1) * 8192 + 512);
            }
            acc0 = __builtin_amdgcn_mfma_f32_32x32x16_bf16(a_c, b0_c, acc0, 0, 0, 0);
            acc1 = __builtin_amdgcn_mfma_f32_32x32x16_bf16(a_c, b1_c, acc1, 0, 0, 0);
            if (k0 < 31) { a_c = a_n; b0_c = b0_n; b1_c = b1_n; }
        }

        // ---- epilogue: out = p + acc (p already in regs)
        #pragma unroll
        for (int reg = 0; reg < 16; ++reg) {
            int r = (reg & 3) + 8 * (reg >> 2) + rsub;
            size_t g = (trow0 + r) * 1024;
            out[g + col0]      = pv0[reg] + acc0[reg];
            out[g + col0 + 32] = pv1[reg] + acc1[reg];
        }

        // ---- drain next-tile loads: q passthrough + bf16/swizzle LDS write
        if (t + 1 < TILES) {
            unsigned short* qn = qs[(t + 1) & 1];
            #pragma unroll
            for (int j = 0; j < 8; ++j) {
                int flat = (tid + j * THREADS) * 4;
                int r = flat >> 9, c = flat & 511;
                size_t g = (trow0 + BM + r) * 1024 + 512 + c;
                *(f32x4*)(out + g) = nv[j];
                unsigned lo = f2bf(nv[j].x) | (f2bf(nv[j].y) << 16);
                unsigned hi = f2bf(nv[j].z) | (f2bf(nv[j].w) << 16);
                int bo = (c * 2) ^ ((r & 15) << 4);
                *(uint2*)((char*)qn + r * 1024 + bo) = make_uint2(lo, hi);
            }
        }
        __syncthreads();   // next iter reads qs[(t+1)&1]; writes to qs[t&1] wait too
    }
}

extern "C" void kernel_launch(void* const* d_in, const int* in_sizes, int n_in,
                              void* d_out, int out_size, void* d_ws, size_t ws_size,
                              hipStream_t stream) {
    const float* pq = (const float*)d_in[0];
    const float* A  = (const float*)d_in[1];
    float* out = (float*)d_out;
    unsigned short* Sf = (unsigned short*)d_ws;   // 512 KB fragment-ordered S

    prep_Sfrag<<<128, 256, 0, stream>>>(A, Sf);
    gemm_kernel<<<NBLK, THREADS, 0, stream>>>(pq, Sf, out);
}

// Round 4
// 135.230 us; speedup vs baseline: 2.5420x; 2.5420x over previous
//
#include <hip/hip_runtime.h>

#define DIM 512
#define BATCH 65536
#define BM 32
#define THREADS 512

typedef float f32x4 __attribute__((ext_vector_type(4)));
typedef float f32x16 __attribute__((ext_vector_type(16)));
typedef __bf16 bf16x8 __attribute__((ext_vector_type(8)));

__device__ __forceinline__ unsigned f2bf(float f) {
    unsigned u = __float_as_uint(f);
    return (u + 0x7FFFu + ((u >> 16) & 1u)) >> 16;
}

// Sf in MFMA-B-fragment order: Sf[((k0*16 + np)*64 + lane)*8 + j]
//   = bf16( A[n][k] + A[k][n] ),  n = np*32 + (lane&31),  k = k0*16 + (lane>>5)*8 + j
__global__ void prep_Sfrag(const float* __restrict__ A, unsigned short* __restrict__ Sf) {
    int idx = blockIdx.x * 256 + threadIdx.x;    // 0..32767 : (k0, np, lane)
    int lane = idx & 63;
    int np   = (idx >> 6) & 15;
    int k0   = idx >> 10;
    int n     = np * 32 + (lane & 31);
    int kbase = k0 * 16 + (lane >> 5) * 8;
    unsigned short tmp[8];
    #pragma unroll
    for (int j = 0; j < 8; ++j) {
        int k = kbase + j;
        tmp[j] = (unsigned short)f2bf(A[n * DIM + k] + A[k * DIM + n]);
    }
    *(uint4*)(Sf + (size_t)idx * 8) = *(const uint4*)tmp;
}

// out[b][0:512] = p[b] + q[b].S ; out[b][512:1024] = q[b]
__global__ __launch_bounds__(THREADS, 4)
void gemm_kernel(const float* __restrict__ pq,
                 const unsigned short* __restrict__ Sf,
                 float* __restrict__ out) {
    __shared__ unsigned short qs[BM * DIM];   // 32 KB: bf16 q tile, then f32 acc scratch
    const int rb  = blockIdx.x * BM;
    const int tid = threadIdx.x;
    const int wid  = tid >> 6;
    const int lane = tid & 63;
    const int row  = lane & 31;
    const int khalf = lane >> 5;

    // ---- Stage q tile -> LDS (bf16, swizzled); fuse q -> out[:,512:] passthrough
    #pragma unroll
    for (int i = 0; i < 8; ++i) {
        int flat = (tid + i * THREADS) * 4;
        int r = flat >> 9, c = flat & 511;
        size_t g = (size_t)(rb + r) * 1024 + 512 + c;
        f32x4 v = __builtin_nontemporal_load((const f32x4*)(pq + g));
        __builtin_nontemporal_store(v, (f32x4*)(out + g));
        unsigned lo = f2bf(v.x) | (f2bf(v.y) << 16);
        unsigned hi = f2bf(v.z) | (f2bf(v.w) << 16);
        int bo = (c * 2) ^ ((r & 15) << 4);
        *(uint2*)((char*)qs + r * 1024 + bo) = make_uint2(lo, hi);
    }
    __syncthreads();

    // ---- k-loop: manual depth-2 register pipeline
    const unsigned short* Sfp = Sf + ((size_t)(wid * 2) * 64 + lane) * 8;
    f32x16 acc0 = {}, acc1 = {};
    bf16x8 a_c  = *(const bf16x8*)((const char*)qs + row * 1024 +
                                   ((khalf * 16) ^ ((row & 15) << 4)));
    bf16x8 b0_c = *(const bf16x8*)(Sfp);
    bf16x8 b1_c = *(const bf16x8*)(Sfp + 512);
    #pragma unroll
    for (int k0 = 0; k0 < 32; ++k0) {
        bf16x8 a_n, b0_n, b1_n;
        if (k0 < 31) {
            int bo = ((k0 + 1) * 32 + khalf * 16) ^ ((row & 15) << 4);
            a_n  = *(const bf16x8*)((const char*)qs + row * 1024 + bo);
            b0_n = *(const bf16x8*)(Sfp + (size_t)(k0 + 1) * 8192);
            b1_n = *(const bf16x8*)(Sfp + (size_t)(k0 + 1) * 8192 + 512);
        }
        acc0 = __builtin_amdgcn_mfma_f32_32x32x16_bf16(a_c, b0_c, acc0, 0, 0, 0);
        acc1 = __builtin_amdgcn_mfma_f32_32x32x16_bf16(a_c, b1_c, acc1, 0, 0, 0);
        if (k0 < 31) { a_c = a_n; b0_c = b0_n; b1_c = b1_n; }
    }

    // ---- Epilogue: vectorize via LDS round-trip (qs is free now).
    // sc[32][256] f32: wave w's 32x32 panel tile at col block w*32.
    float* sc = (float*)qs;
    __syncthreads();                       // all waves done reading qs
    #pragma unroll
    for (int pass = 0; pass < 2; ++pass) {
        const f32x16& ac = pass ? acc1 : acc0;
        #pragma unroll
        for (int reg = 0; reg < 16; ++reg) {
            int r = (reg & 3) + 8 * (reg >> 2) + 4 * khalf;
            sc[r * 256 + wid * 32 + row] = ac[reg];   // 2-way bank alias: free
        }
        __syncthreads();
        #pragma unroll
        for (int j = 0; j < 4; ++j) {
            int c  = tid + j * 512;                    // 0..2047
            int r  = c >> 6, cc = c & 63;
            int gcol = (cc >> 3) * 64 + (cc & 7) * 4 + pass * 32;
            size_t g = (size_t)(rb + r) * 1024 + gcol;
            f32x4 v  = *(const f32x4*)(sc + r * 256 + cc * 4);
            f32x4 pv = __builtin_nontemporal_load((const f32x4*)(pq + g));
            __builtin_nontemporal_store(pv + v, (f32x4*)(out + g));
        }
        __syncthreads();
    }
}

extern "C" void kernel_launch(void* const* d_in, const int* in_sizes, int n_in,
                              void* d_out, int out_size, void* d_ws, size_t ws_size,
                              hipStream_t stream) {
    const float* pq = (const float*)d_in[0];
    const float* A  = (const float*)d_in[1];
    float* out = (float*)d_out;
    unsigned short* Sf = (unsigned short*)d_ws;   // 512 KB fragment-ordered S

    prep_Sfrag<<<128, 256, 0, stream>>>(A, Sf);
    gemm_kernel<<<BATCH / BM, THREADS, 0, stream>>>(pq, Sf, out);
}